// Round 4
// baseline (1395.608 us; speedup 1.0000x reference)
//
#include <hip/hip_runtime.h>

namespace {
constexpr int Hn = 512, Wn = 512, Cn = 32, Gn = 16;
constexpr int WHn = 227, WWn = 227;
constexpr int OHn = Hn - WHn;        // 285
constexpr int OWn = Wn - WWn;        // 285
constexpr int PTn = (Hn - OHn) / 2;  // 113
constexpr int PLn = (Wn - OWn) / 2;  // 113
constexpr float EPSn = 1e-5f;
constexpr int VCHUNK = 64;           // K1 rows per block (8 chunks of 64)
constexpr int NHC = 16, HPC = 18;    // K2: 16 h-chunks of 18 output rows
}

// K1: local vertical inclusive prefix of (S = x0+x1, Q = x0^2+x1^2) per
// 64-row chunk, written as float2 (S,Q) into P (aliased onto d_out; K3
// fully overwrites d_out later). Pure streaming: x read once, P written
// once. Block = (group, chunk); thread owns 2 columns (float2 loads,
// float4 store). 8-row unroll = 16 loads in flight per lane.
__global__ __launch_bounds__(256, 8) void lcn_vprefix(const float* __restrict__ x,
                                                      float2* __restrict__ P) {
  const int blk = blockIdx.x;          // g*8 + k
  const int g = blk >> 3;
  const int k = blk & 7;
  const int t = threadIdx.x;           // cols 2t, 2t+1

  const float2* __restrict__ x0 =
      reinterpret_cast<const float2*>(x + (size_t)(g * 2) * Hn * Wn) + t;
  const float2* __restrict__ x1 = x0 + (size_t)Hn * Wn / 2;
  float4* __restrict__ Pg4 =
      reinterpret_cast<float4*>(P + (size_t)g * Hn * Wn) + t;

  const int r0 = k * VCHUNK;
  float s0 = 0.f, q0 = 0.f, s1 = 0.f, q1 = 0.f;
  for (int i = 0; i < VCHUNK; i += 8) {
    float2 a[8], b[8];
    #pragma unroll
    for (int j = 0; j < 8; ++j) {
      a[j] = x0[(size_t)(r0 + i + j) * (Wn / 2)];
      b[j] = x1[(size_t)(r0 + i + j) * (Wn / 2)];
    }
    #pragma unroll
    for (int j = 0; j < 8; ++j) {
      s0 += a[j].x + b[j].x;
      q0 += a[j].x * a[j].x + b[j].x * b[j].x;
      s1 += a[j].y + b[j].y;
      q1 += a[j].y * a[j].y + b[j].y * b[j].y;
      Pg4[(size_t)(r0 + i + j) * (Wn / 2)] = make_float4(s0, q0, s1, q1);
    }
  }
}

// K2: stats from P. V(h,w) = Pglob(h+227,w) - Pglob(h,w) where
// Pglob(r) = Plocal(r) + sum of chunk-last rows (T_j, j < chunk(r)).
// Within an 18-row h-chunk, chunk(h) and chunk(h+227) each take at most 2
// values -> 4 register snapshots of the T-prefix (no dynamic reg indexing).
// Rows are fully independent: no ramp, no re-read amplification.
// Horizontal 227-window via 512-wide scan, 4 rows per barrier-group.
__global__ __launch_bounds__(512, 8) void lcn_stats2(const float2* __restrict__ P,
                                                     float2* __restrict__ stats) {
  const int blk = blockIdx.x;          // g*NHC + hc
  const int g = blk / NHC;
  const int hc = blk - g * NHC;
  const int w = threadIdx.x;
  const int lane = w & 63;
  const int wid = w >> 6;

  const int h0 = hc * HPC;
  const int h1 = min(OHn, h0 + HPC);
  const float2* __restrict__ Pg = P + (size_t)g * Hn * Wn + w;  // row stride Wn

  // T-prefix snapshots at the (<=4) chunk indices this block needs.
  const int kb0 = h0 >> 6, kb1 = (h1 - 1) >> 6;
  const int ka0 = (h0 + WHn) >> 6, ka1 = (h1 - 1 + WHn) >> 6;
  float2 Bkb0 = {0.f, 0.f}, Bkb1 = {0.f, 0.f};
  float2 Bka0 = {0.f, 0.f}, Bka1 = {0.f, 0.f};
  {
    float2 acc = {0.f, 0.f};
    #pragma unroll
    for (int j = 0; j < 7; ++j) {
      float2 T = Pg[(size_t)(j * 64 + 63) * Wn];
      acc.x += T.x; acc.y += T.y;
      if (j + 1 == kb0) Bkb0 = acc;
      if (j + 1 == kb1) Bkb1 = acc;
      if (j + 1 == ka0) Bka0 = acc;
      if (j + 1 == ka1) Bka1 = acc;
    }
  }

  __shared__ float2 Ps[4][Wn + 1];
  __shared__ float2 wsum[8][4];
  const float inv_n = 1.0f / (float)(WHn * WWn * 2);

  float2 pa[4], pb[4];
  auto prefetch = [&](int hb) {
    #pragma unroll
    for (int j = 0; j < 4; ++j) {
      int ra = min(hb + j + WHn, Hn - 1);   // clamp: guarded rows unused
      int rb = min(hb + j, OHn - 1);
      pa[j] = Pg[(size_t)ra * Wn];
      pb[j] = Pg[(size_t)rb * Wn];
    }
  };
  prefetch(h0);

  for (int h = h0; h < h1; h += 4) {
    // assemble V for 4 rows from prefetched P rows + chunk fixup
    float2 v[4];
    #pragma unroll
    for (int rr = 0; rr < 4; ++rr) {
      int hh = h + rr;
      int kb = hh >> 6, ka = (hh + WHn) >> 6;
      float2 Bb = (kb == kb0) ? Bkb0 : Bkb1;
      float2 Ba = (ka == ka0) ? Bka0 : Bka1;
      v[rr].x = (pa[rr].x + Ba.x) - (pb[rr].x + Bb.x);
      v[rr].y = (pa[rr].y + Ba.y) - (pb[rr].y + Bb.y);
    }

    if (h + 4 < h1) prefetch(h + 4);   // hide latency under the scan

    // 4 independent 512-wide inclusive scans (shared barriers)
    #pragma unroll
    for (int d = 1; d < 64; d <<= 1) {
      #pragma unroll
      for (int rr = 0; rr < 4; ++rr) {
        float sx = __shfl_up(v[rr].x, d, 64);
        float sy = __shfl_up(v[rr].y, d, 64);
        if (lane >= d) { v[rr].x += sx; v[rr].y += sy; }
      }
    }
    if (lane == 63) {
      #pragma unroll
      for (int rr = 0; rr < 4; ++rr) wsum[wid][rr] = v[rr];
    }
    __syncthreads();
    float2 off[4] = {{0.f,0.f},{0.f,0.f},{0.f,0.f},{0.f,0.f}};
    #pragma unroll
    for (int i = 0; i < 7; ++i) {
      if (i < wid) {
        #pragma unroll
        for (int rr = 0; rr < 4; ++rr) {
          off[rr].x += wsum[i][rr].x; off[rr].y += wsum[i][rr].y;
        }
      }
    }
    #pragma unroll
    for (int rr = 0; rr < 4; ++rr)
      Ps[rr][w + 1] = make_float2(v[rr].x + off[rr].x, v[rr].y + off[rr].y);
    __syncthreads();

    if (w < OWn) {
      #pragma unroll
      for (int rr = 0; rr < 4; ++rr) {
        if (h + rr < h1) {
          float2 hi = Ps[rr][w + WWn + 1];
          float2 lo = Ps[rr][w + 1];
          float S = hi.x - lo.x;
          float Q = hi.y - lo.y;
          float mean = S * inv_n;
          float var = (Q - S * S * inv_n) * inv_n;
          float istd = rsqrtf(var + EPSn);
          stats[((size_t)g * OHn + (h + rr)) * OWn + w] = make_float2(mean, istd);
        }
      }
    }
    __syncthreads();
  }
}

// K3: out = (x - mean) * invstd * weight[c] + bias[c], float4-vectorized.
__global__ __launch_bounds__(256) void lcn_norm(const float* __restrict__ x,
                                                const float* __restrict__ weight,
                                                const float* __restrict__ bias,
                                                const float2* __restrict__ stats,
                                                float* __restrict__ out) {
  const size_t idx = (size_t)blockIdx.x * blockDim.x + threadIdx.x; // float4 id
  const int w4 = (int)(idx & (Wn / 4 - 1));       // 0..127
  const size_t row = idx >> 7;                    // (n*32+c)*512 + hh
  const int hh = (int)(row & (Hn - 1));
  const int c = (int)((row >> 9) & (Cn - 1));
  const int n = (int)(row >> 14);
  const int g = c >> 1;

  const int hp = min(max(hh - PTn, 0), OHn - 1);
  const float2* __restrict__ srow =
      stats + ((size_t)(n * Gn + g) * OHn + hp) * OWn;
  const float wt = weight[c];
  const float bs = bias[c];

  const float4 xv = reinterpret_cast<const float4*>(x)[idx];
  float4 ov;
  const int wwb = w4 * 4;
  {
    int wp = min(max(wwb + 0 - PLn, 0), OWn - 1);
    float2 mv = srow[wp];
    ov.x = (xv.x - mv.x) * mv.y * wt + bs;
  }
  {
    int wp = min(max(wwb + 1 - PLn, 0), OWn - 1);
    float2 mv = srow[wp];
    ov.y = (xv.y - mv.x) * mv.y * wt + bs;
  }
  {
    int wp = min(max(wwb + 2 - PLn, 0), OWn - 1);
    float2 mv = srow[wp];
    ov.z = (xv.z - mv.x) * mv.y * wt + bs;
  }
  {
    int wp = min(max(wwb + 3 - PLn, 0), OWn - 1);
    float2 mv = srow[wp];
    ov.w = (xv.w - mv.x) * mv.y * wt + bs;
  }
  reinterpret_cast<float4*>(out)[idx] = ov;
}

extern "C" void kernel_launch(void* const* d_in, const int* in_sizes, int n_in,
                              void* d_out, int out_size, void* d_ws, size_t ws_size,
                              hipStream_t stream) {
  const float* x = (const float*)d_in[0];
  const float* weight = (const float*)d_in[1];
  const float* bias = (const float*)d_in[2];
  float* out = (float*)d_out;
  float2* P = (float2*)d_out;     // P is exactly out-sized (128*512*512*8 B);
                                  // K3 overwrites d_out afterwards.
  float2* stats = (float2*)d_ws;  // 128*285*285*8 = 83,174,400 B (proven fit)

  hipLaunchKernelGGL(lcn_vprefix, dim3(128 * 8), dim3(256), 0, stream, x, P);
  hipLaunchKernelGGL(lcn_stats2, dim3(128 * NHC), dim3(512), 0, stream,
                     P, stats);

  const int total4 = (8 * Cn * Hn * Wn) / 4;      // 16,777,216 float4s
  hipLaunchKernelGGL(lcn_norm, dim3(total4 / 256), dim3(256), 0, stream,
                     x, weight, bias, stats, out);
}

// Round 5
// 246.623 us; speedup vs baseline: 5.6589x; 5.6589x over previous
//
#include <hip/hip_runtime.h>

namespace {
constexpr int Hn = 512, Wn = 512, Cn = 32, Gn = 16;
constexpr int WHn = 227, WWn = 227;
constexpr int OHn = Hn - WHn;        // 285
constexpr int OWn = Wn - WWn;        // 285
constexpr int PTn = (Hn - OHn) / 2;  // 113
constexpr int PLn = (Wn - OWn) / 2;  // 113
constexpr float EPSn = 1e-5f;
constexpr int CHUNKS = 4;            // row-chunks per group -> 512 blocks
constexpr int RPC = 72;              // rows per chunk (last chunk: 69)
}

// One block per (group, chunk-of-rows). 512 threads.
// Ramp (rows h0+1..h0+227, both channels) is computed as a flat float4
// stream: thread = (column-quad q, row-phase p); per-thread partial (S,Q)
// per column, then one LDS transpose (reusing Ps) gives thread w column
// w's window sum. Then the proven f32 sliding window + 512-wide scan,
// 4 output rows per barrier-group, next rows prefetched under the scan.
// Window for stat (h,w): input rows h+1..h+227, cols w+1..w+227.
__global__ __launch_bounds__(512, 4) void lcn_stats(const float* __restrict__ x,
                                                    float2* __restrict__ stats) {
  const int blk = blockIdx.x;
  const int chunk = blk & (CHUNKS - 1);
  const int g = blk >> 2;            // 0..127 == n*16 + group
  const int w = threadIdx.x;
  const int lane = w & 63;
  const int wid = w >> 6;

  const float* __restrict__ x0 = x + (size_t)(g * 2) * Hn * Wn;
  const float* __restrict__ x1 = x0 + (size_t)Hn * Wn;

  const int h0 = chunk * RPC;
  const int h1 = min(OHn, h0 + RPC);

  __shared__ __align__(16) float2 Ps[4][Wn + 1];   // scan buffer / transpose
  __shared__ float2 wsum[8][4];

  // ---- ramp: flat float4 streaming over rows h0+1 .. h0+227, 2 channels
  const int q = w & 127;             // column quad: cols 4q..4q+3
  const int p = w >> 7;              // row phase 0..3
  float4 sS = {0.f, 0.f, 0.f, 0.f}, sQ = {0.f, 0.f, 0.f, 0.f};
  {
    const float4* __restrict__ r0 =
        reinterpret_cast<const float4*>(x0 + (size_t)(h0 + 1) * Wn) + q;
    const float4* __restrict__ r1 =
        reinterpret_cast<const float4*>(x1 + (size_t)(h0 + 1) * Wn) + q;
    #pragma unroll 4
    for (int r = p; r < WHn; r += 4) {
      float4 a = r0[(size_t)r * (Wn / 4)];
      float4 b = r1[(size_t)r * (Wn / 4)];
      sS.x += a.x + b.x; sQ.x += a.x * a.x + b.x * b.x;
      sS.y += a.y + b.y; sQ.y += a.y * a.y + b.y * b.y;
      sS.z += a.z + b.z; sQ.z += a.z * a.z + b.z * b.z;
      sS.w += a.w + b.w; sQ.w += a.w * a.w + b.w * b.w;
    }
  }
  // transpose partials: colacc[p][col] = (S,Q); thread w sums its column.
  float accS, accQ;
  {
    float4* cc = reinterpret_cast<float4*>(&Ps[0][0]);   // [4][256] float4
    cc[p * 256 + 2 * q]     = make_float4(sS.x, sQ.x, sS.y, sQ.y);
    cc[p * 256 + 2 * q + 1] = make_float4(sS.z, sQ.z, sS.w, sQ.w);
    __syncthreads();
    const float2* cf = reinterpret_cast<const float2*>(&Ps[0][0]); // [4][512]
    float2 t0 = cf[0 * Wn + w], t1 = cf[1 * Wn + w];
    float2 t2 = cf[2 * Wn + w], t3 = cf[3 * Wn + w];
    accS = (t0.x + t1.x) + (t2.x + t3.x);
    accQ = (t0.y + t1.y) + (t2.y + t3.y);
    __syncthreads();   // Ps free for scan reuse
  }

  const float inv_n = 1.0f / (float)(WHn * WWn * 2);

  // prefetch registers: add rows h+228+j, sub rows h+1+j (j=0..3), 2 channels
  float pa0[4], pa1[4], ps0[4], ps1[4];
  auto prefetch = [&](int hb) {
    #pragma unroll
    for (int j = 0; j < 4; ++j) {
      int ra = min(hb + WHn + 1 + j, Hn - 1);   // clamp: guarded rows unused
      int rs = hb + 1 + j;
      pa0[j] = x0[(size_t)ra * Wn + w];
      pa1[j] = x1[(size_t)ra * Wn + w];
      ps0[j] = x0[(size_t)rs * Wn + w];
      ps1[j] = x1[(size_t)rs * Wn + w];
    }
  };
  prefetch(h0);

  for (int h = h0; h < h1; h += 4) {
    // consume prefetched rows: v[rr] = window(h+rr); acc -> window(h+4)
    float2 v[4];
    v[0] = make_float2(accS, accQ);
    float s2 = accS, q2 = accQ;
    #pragma unroll
    for (int j = 0; j < 3; ++j) {
      s2 += (pa0[j] + pa1[j]) - (ps0[j] + ps1[j]);
      q2 += (pa0[j] * pa0[j] + pa1[j] * pa1[j])
          - (ps0[j] * ps0[j] + ps1[j] * ps1[j]);
      v[j + 1] = make_float2(s2, q2);
    }
    s2 += (pa0[3] + pa1[3]) - (ps0[3] + ps1[3]);
    q2 += (pa0[3] * pa0[3] + pa1[3] * pa1[3])
        - (ps0[3] * ps0[3] + ps1[3] * ps1[3]);
    accS = s2; accQ = q2;

    // issue next iteration's loads; latency hides under the scan
    if (h + 4 < h1) prefetch(h + 4);

    // 4 independent 512-wide inclusive scans (shared barriers)
    #pragma unroll
    for (int d = 1; d < 64; d <<= 1) {
      #pragma unroll
      for (int rr = 0; rr < 4; ++rr) {
        float sx = __shfl_up(v[rr].x, d, 64);
        float sy = __shfl_up(v[rr].y, d, 64);
        if (lane >= d) { v[rr].x += sx; v[rr].y += sy; }
      }
    }
    if (lane == 63) {
      #pragma unroll
      for (int rr = 0; rr < 4; ++rr) wsum[wid][rr] = v[rr];
    }
    __syncthreads();
    float2 off[4] = {{0.f,0.f},{0.f,0.f},{0.f,0.f},{0.f,0.f}};
    #pragma unroll
    for (int i = 0; i < 7; ++i) {
      if (i < wid) {
        #pragma unroll
        for (int rr = 0; rr < 4; ++rr) {
          off[rr].x += wsum[i][rr].x; off[rr].y += wsum[i][rr].y;
        }
      }
    }
    #pragma unroll
    for (int rr = 0; rr < 4; ++rr)
      Ps[rr][w + 1] = make_float2(v[rr].x + off[rr].x, v[rr].y + off[rr].y);
    __syncthreads();

    if (w < OWn) {
      #pragma unroll
      for (int rr = 0; rr < 4; ++rr) {
        if (h + rr < h1) {
          float2 hi = Ps[rr][w + WWn + 1];
          float2 lo = Ps[rr][w + 1];
          float S = hi.x - lo.x;
          float Q = hi.y - lo.y;
          float mean = S * inv_n;
          float var = (Q - S * S * inv_n) * inv_n;
          float istd = rsqrtf(var + EPSn);
          stats[((size_t)g * OHn + (h + rr)) * OWn + w] = make_float2(mean, istd);
        }
      }
    }
    __syncthreads();   // protect Ps/wsum before next iteration rewrites
  }
}

// out = (x - mean) * invstd * weight[c] + bias[c], float4-vectorized.
__global__ __launch_bounds__(256) void lcn_norm(const float* __restrict__ x,
                                                const float* __restrict__ weight,
                                                const float* __restrict__ bias,
                                                const float2* __restrict__ stats,
                                                float* __restrict__ out) {
  const size_t idx = (size_t)blockIdx.x * blockDim.x + threadIdx.x; // float4 id
  const int w4 = (int)(idx & (Wn / 4 - 1));       // 0..127
  const size_t row = idx >> 7;                    // (n*32+c)*512 + hh
  const int hh = (int)(row & (Hn - 1));
  const int c = (int)((row >> 9) & (Cn - 1));
  const int n = (int)(row >> 14);
  const int g = c >> 1;

  const int hp = min(max(hh - PTn, 0), OHn - 1);
  const float2* __restrict__ srow =
      stats + ((size_t)(n * Gn + g) * OHn + hp) * OWn;
  const float wt = weight[c];
  const float bs = bias[c];

  const float4 xv = reinterpret_cast<const float4*>(x)[idx];
  float4 ov;
  const int wwb = w4 * 4;
  {
    int wp = min(max(wwb + 0 - PLn, 0), OWn - 1);
    float2 mv = srow[wp];
    ov.x = (xv.x - mv.x) * mv.y * wt + bs;
  }
  {
    int wp = min(max(wwb + 1 - PLn, 0), OWn - 1);
    float2 mv = srow[wp];
    ov.y = (xv.y - mv.x) * mv.y * wt + bs;
  }
  {
    int wp = min(max(wwb + 2 - PLn, 0), OWn - 1);
    float2 mv = srow[wp];
    ov.z = (xv.z - mv.x) * mv.y * wt + bs;
  }
  {
    int wp = min(max(wwb + 3 - PLn, 0), OWn - 1);
    float2 mv = srow[wp];
    ov.w = (xv.w - mv.x) * mv.y * wt + bs;
  }
  reinterpret_cast<float4*>(out)[idx] = ov;
}

extern "C" void kernel_launch(void* const* d_in, const int* in_sizes, int n_in,
                              void* d_out, int out_size, void* d_ws, size_t ws_size,
                              hipStream_t stream) {
  const float* x = (const float*)d_in[0];
  const float* weight = (const float*)d_in[1];
  const float* bias = (const float*)d_in[2];
  float* out = (float*)d_out;
  float2* stats = (float2*)d_ws;  // 128*285*285*8 = 83,174,400 B (fits ws)

  hipLaunchKernelGGL(lcn_stats, dim3(128 * CHUNKS), dim3(512), 0, stream,
                     x, stats);

  const int total4 = (8 * Cn * Hn * Wn) / 4;      // 16,777,216 float4s
  hipLaunchKernelGGL(lcn_norm, dim3(total4 / 256), dim3(256), 0, stream,
                     x, weight, bias, stats, out);
}

// Round 7
// 204.424 us; speedup vs baseline: 6.8270x; 1.2064x over previous
//
#include <hip/hip_runtime.h>

namespace {
constexpr int Hn = 512, Wn = 512;
constexpr int WHn = 227, WWn = 227;
constexpr int OHn = Hn - WHn;        // 285
constexpr int OWn = Wn - WWn;        // 285
constexpr int PTn = 113, PLn = 113;  // replicate-pad offsets
constexpr float EPSn = 1e-5f;
}

// Fully fused LocalContextNorm. One block per (group, chunk). 512 threads.
// Phase A: ramp = flat float4 stream of rows h0+1..h0+227 (both channels),
//          LDS-transposed to per-column (S,Q) window sums.
// Phase B: per 4 stat rows: f32 vertical slide + 512-wide scan -> window
//          sums in Ps; then NORMALIZE out rows hh = sh+113 directly from Ps
//          (col ww uses stat col clamp(ww-113)). No stats buffer at all.
// Phase C: chunk 0 streams border rows 0..112 (stat row 0), chunk 3 streams
//          rows 398..511 (stat row 284), stats saved in bstat LDS.
// Stat-row split {44,100,100,41} balances border streaming across chunks.
// Window for stat (h,w): input rows h+1..h+227, cols w+1..w+227.
__global__ __launch_bounds__(512, 4) void lcn_fused(const float* __restrict__ x,
                                                    const float* __restrict__ weight,
                                                    const float* __restrict__ bias,
                                                    float* __restrict__ out) {
  const int blk = blockIdx.x;
  const int chunk = blk & 3;
  const int g = blk >> 2;            // 0..127 global group (n*16 + gg)
  const int w = threadIdx.x;
  const int lane = w & 63;
  const int wid = w >> 6;

  const float* __restrict__ x0 = x + (size_t)(g * 2) * Hn * Wn;
  const float* __restrict__ x1 = x0 + (size_t)Hn * Wn;
  float* __restrict__ o0 = out + (size_t)(g * 2) * Hn * Wn;
  float* __restrict__ o1 = o0 + (size_t)Hn * Wn;
  // weight/bias have 32 entries: index by channel WITHIN the image, not by
  // global group (g*2 would run to 254 -> OOB garbage; round-6 bug).
  const int cch = (g & 15) * 2;
  const float wt0 = weight[cch], wt1 = weight[cch + 1];
  const float bs0 = bias[cch], bs1 = bias[cch + 1];

  const int h0 = chunk == 0 ? 0 : chunk == 1 ? 44 : chunk == 2 ? 144 : 244;
  const int h1 = chunk == 0 ? 44 : chunk == 1 ? 144 : chunk == 2 ? 244 : 285;

  __shared__ __align__(16) float2 Ps[4][Wn + 1];   // scan buffer / transpose
  __shared__ float2 wsum[8][4];
  __shared__ float2 bstat[4][132];   // border stats, transposed [j][quad]

  // ---- Phase A: ramp as flat float4 stream, 16 loads in flight ----
  const int q = w & 127;             // column quad: cols 4q..4q+3
  const int p = w >> 7;              // row phase 0..3
  float4 sS = {0.f, 0.f, 0.f, 0.f}, sQ = {0.f, 0.f, 0.f, 0.f};
  {
    const float4* __restrict__ r0 =
        reinterpret_cast<const float4*>(x0 + (size_t)(h0 + 1) * Wn) + q;
    const float4* __restrict__ r1 =
        reinterpret_cast<const float4*>(x1 + (size_t)(h0 + 1) * Wn) + q;
    #pragma unroll 8
    for (int r = p; r < WHn; r += 4) {
      float4 a = r0[(size_t)r * (Wn / 4)];
      float4 b = r1[(size_t)r * (Wn / 4)];
      sS.x += a.x + b.x; sQ.x += a.x * a.x + b.x * b.x;
      sS.y += a.y + b.y; sQ.y += a.y * a.y + b.y * b.y;
      sS.z += a.z + b.z; sQ.z += a.z * a.z + b.z * b.z;
      sS.w += a.w + b.w; sQ.w += a.w * a.w + b.w * b.w;
    }
  }
  float accS, accQ;
  {
    float4* cc = reinterpret_cast<float4*>(&Ps[0][0]);   // [4][256] float4
    cc[p * 256 + 2 * q]     = make_float4(sS.x, sQ.x, sS.y, sQ.y);
    cc[p * 256 + 2 * q + 1] = make_float4(sS.z, sQ.z, sS.w, sQ.w);
    __syncthreads();
    const float2* cf = reinterpret_cast<const float2*>(&Ps[0][0]); // [4][512]
    float2 t0 = cf[0 * Wn + w], t1 = cf[1 * Wn + w];
    float2 t2 = cf[2 * Wn + w], t3 = cf[3 * Wn + w];
    accS = (t0.x + t1.x) + (t2.x + t3.x);
    accQ = (t0.y + t1.y) + (t2.y + t3.y);
    __syncthreads();   // Ps free for scan reuse
  }

  const float inv_n = 1.0f / (float)(WHn * WWn * 2);
  const int wp = min(max(w - PLn, 0), OWn - 1);   // out-col -> stat-col

  // slide prefetch: add rows h+228+j, sub rows h+1+j (j=0..3), 2 channels
  float pa0[4], pa1[4], ps0[4], ps1[4];
  auto prefetch = [&](int hb) {
    #pragma unroll
    for (int j = 0; j < 4; ++j) {
      int ra = min(hb + WHn + 1 + j, Hn - 1);   // clamp: guarded rows unused
      int rs = hb + 1 + j;
      pa0[j] = x0[(size_t)ra * Wn + w];
      pa1[j] = x1[(size_t)ra * Wn + w];
      ps0[j] = x0[(size_t)rs * Wn + w];
      ps1[j] = x1[(size_t)rs * Wn + w];
    }
  };
  prefetch(h0);

  // ---- Phase B: slide + scan + fused normalize ----
  for (int h = h0; h < h1; h += 4) {
    float2 v[4];
    v[0] = make_float2(accS, accQ);
    float s2 = accS, q2 = accQ;
    #pragma unroll
    for (int j = 0; j < 3; ++j) {
      s2 += (pa0[j] + pa1[j]) - (ps0[j] + ps1[j]);
      q2 += (pa0[j] * pa0[j] + pa1[j] * pa1[j])
          - (ps0[j] * ps0[j] + ps1[j] * ps1[j]);
      v[j + 1] = make_float2(s2, q2);
    }
    s2 += (pa0[3] + pa1[3]) - (ps0[3] + ps1[3]);
    q2 += (pa0[3] * pa0[3] + pa1[3] * pa1[3])
        - (ps0[3] * ps0[3] + ps1[3] * ps1[3]);
    accS = s2; accQ = q2;

    // issue next slide loads + this iteration's norm-x loads; hide under scan
    if (h + 4 < h1) prefetch(h + 4);
    float xa[4], xb[4];
    #pragma unroll
    for (int rr = 0; rr < 4; ++rr) {
      const size_t hh = (size_t)(h + PTn + rr) * Wn + w;  // max row 400 < 512
      xa[rr] = x0[hh];
      xb[rr] = x1[hh];
    }

    // 4 independent 512-wide inclusive scans (shared barriers)
    #pragma unroll
    for (int d = 1; d < 64; d <<= 1) {
      #pragma unroll
      for (int rr = 0; rr < 4; ++rr) {
        float sx = __shfl_up(v[rr].x, d, 64);
        float sy = __shfl_up(v[rr].y, d, 64);
        if (lane >= d) { v[rr].x += sx; v[rr].y += sy; }
      }
    }
    if (lane == 63) {
      #pragma unroll
      for (int rr = 0; rr < 4; ++rr) wsum[wid][rr] = v[rr];
    }
    __syncthreads();
    float2 off[4] = {{0.f,0.f},{0.f,0.f},{0.f,0.f},{0.f,0.f}};
    #pragma unroll
    for (int i = 0; i < 7; ++i) {
      if (i < wid) {
        #pragma unroll
        for (int rr = 0; rr < 4; ++rr) {
          off[rr].x += wsum[i][rr].x; off[rr].y += wsum[i][rr].y;
        }
      }
    }
    #pragma unroll
    for (int rr = 0; rr < 4; ++rr)
      Ps[rr][w + 1] = make_float2(v[rr].x + off[rr].x, v[rr].y + off[rr].y);
    __syncthreads();

    // fused normalize: out row hh = (h+rr)+113 from stat row h+rr
    #pragma unroll
    for (int rr = 0; rr < 4; ++rr) {
      if (h + rr < h1) {
        float2 hi = Ps[rr][wp + WWn + 1];
        float2 lo = Ps[rr][wp + 1];
        float S = hi.x - lo.x;
        float Q = hi.y - lo.y;
        float mean = S * inv_n;
        float var = (Q - S * S * inv_n) * inv_n;
        float istd = rsqrtf(var + EPSn);
        if (rr == 0 && ((chunk == 0 && h == 0) || (chunk == 3 && h == 284)))
          bstat[w & 3][w >> 2] = make_float2(mean, istd);
        const size_t oo = (size_t)(h + PTn + rr) * Wn + w;
        o0[oo] = (xa[rr] - mean) * istd * wt0 + bs0;
        o1[oo] = (xb[rr] - mean) * istd * wt1 + bs1;
      }
    }
    __syncthreads();   // protect Ps/wsum before next iteration rewrites
  }

  // ---- Phase C: replicate-pad border rows (chunk 0: 0..112, chunk 3: 398..511)
  if (chunk == 0 || chunk == 3) {
    const int row0 = (chunk == 0) ? 0 : 398;
    const int nrows = (chunk == 0) ? PTn : Hn - 398;   // 113 / 114
    const int total = nrows * 256;                     // 2 ch x 128 quads
    const float4* __restrict__ xf0 = reinterpret_cast<const float4*>(x0);
    const float4* __restrict__ xf1 = reinterpret_cast<const float4*>(x1);
    float4* __restrict__ of0 = reinterpret_cast<float4*>(o0);
    float4* __restrict__ of1 = reinterpret_cast<float4*>(o1);
    for (int i = w; i < total; i += 512) {
      const int qq = i & 127;
      const int ch = (i >> 7) & 1;
      const int row = row0 + (i >> 8);
      const size_t idx = (size_t)row * (Wn / 4) + qq;
      const float4 xv = ch ? xf1[idx] : xf0[idx];
      const float wt = ch ? wt1 : wt0;
      const float bsv = ch ? bs1 : bs0;
      const float2 m0 = bstat[0][qq];
      const float2 m1 = bstat[1][qq];
      const float2 m2 = bstat[2][qq];
      const float2 m3 = bstat[3][qq];
      float4 ov;
      ov.x = (xv.x - m0.x) * m0.y * wt + bsv;
      ov.y = (xv.y - m1.x) * m1.y * wt + bsv;
      ov.z = (xv.z - m2.x) * m2.y * wt + bsv;
      ov.w = (xv.w - m3.x) * m3.y * wt + bsv;
      if (ch) of1[idx] = ov; else of0[idx] = ov;
    }
  }
}

extern "C" void kernel_launch(void* const* d_in, const int* in_sizes, int n_in,
                              void* d_out, int out_size, void* d_ws, size_t ws_size,
                              hipStream_t stream) {
  const float* x = (const float*)d_in[0];
  const float* weight = (const float*)d_in[1];
  const float* bias = (const float*)d_in[2];
  float* out = (float*)d_out;

  hipLaunchKernelGGL(lcn_fused, dim3(128 * 4), dim3(512), 0, stream,
                     x, weight, bias, out);
}

// Round 8
// 202.567 us; speedup vs baseline: 6.8896x; 1.0092x over previous
//
#include <hip/hip_runtime.h>

namespace {
constexpr int Hn = 512, Wn = 512;
constexpr int WHn = 227, WWn = 227;
constexpr int OHn = Hn - WHn;        // 285
constexpr int OWn = Wn - WWn;        // 285
constexpr int PTn = 113, PLn = 113;  // replicate-pad offsets
constexpr float EPSn = 1e-5f;
}

// Fully fused LocalContextNorm. One block per (group, chunk). 512 threads.
// Round-8 changes vs round-7:
//  * XCD swizzle: B=(X,ghi,chunk) with g=X*16+ghi -> all 4 chunks of a
//    group land on one XCD (B differs by 8), making ramp-overlap and
//    norm-x re-reads L2 hits. (Round-3's failed swizzle scattered 16
//    groups; this keeps chunks of the SAME group together.)
//  * 8 stat rows per iteration + double-buffered Ps -> 2 barriers per 8
//    rows (was 3 per 4). Chunk split {48,96,96,45}.
// Phase A: ramp = flat float4 stream of rows h0+1..h0+227 (both channels),
//          LDS-transposed to per-column (S,Q) window sums.
// Phase B: per 8 stat rows: f32 vertical slide + 512-wide scan -> window
//          sums in Ps[buf]; normalize out rows hh = sh+113 directly.
// Phase C: chunk 0 streams border rows 0..112 (stat row 0), chunk 3 rows
//          398..511 (stat row 284), stats via bstat LDS.
// Window for stat (h,w): input rows h+1..h+227, cols w+1..w+227.
__global__ __launch_bounds__(512, 4) void lcn_fused(const float* __restrict__ x,
                                                    const float* __restrict__ weight,
                                                    const float* __restrict__ bias,
                                                    float* __restrict__ out) {
  const int B = blockIdx.x;
  const int X = B & 7;               // XCD (round-robin heuristic)
  const int s = B >> 3;
  const int chunk = s & 3;
  const int g = X * 16 + (s >> 2);   // 0..127 global group; chunks co-XCD
  const int w = threadIdx.x;
  const int lane = w & 63;
  const int wid = w >> 6;

  const float* __restrict__ x0 = x + (size_t)(g * 2) * Hn * Wn;
  const float* __restrict__ x1 = x0 + (size_t)Hn * Wn;
  float* __restrict__ o0 = out + (size_t)(g * 2) * Hn * Wn;
  float* __restrict__ o1 = o0 + (size_t)Hn * Wn;
  // weight/bias: 32 entries, index by channel within image (round-6 bug).
  const int cch = (g & 15) * 2;
  const float wt0 = weight[cch], wt1 = weight[cch + 1];
  const float bs0 = bias[cch], bs1 = bias[cch + 1];

  const int h0 = chunk == 0 ? 0 : chunk == 1 ? 48 : chunk == 2 ? 144 : 240;
  const int h1 = chunk == 0 ? 48 : chunk == 1 ? 144 : chunk == 2 ? 240 : 285;

  __shared__ __align__(16) float2 Ps[2][8][Wn + 1];  // double-buffered scans
  __shared__ float2 wsum[8][8];
  __shared__ float2 bstat[4][132];   // border stats, transposed [j][quad]

  // ---- Phase A: ramp as flat float4 stream, 16 loads in flight ----
  const int q = w & 127;             // column quad: cols 4q..4q+3
  const int p = w >> 7;              // row phase 0..3
  float4 sS = {0.f, 0.f, 0.f, 0.f}, sQ = {0.f, 0.f, 0.f, 0.f};
  {
    const float4* __restrict__ r0 =
        reinterpret_cast<const float4*>(x0 + (size_t)(h0 + 1) * Wn) + q;
    const float4* __restrict__ r1 =
        reinterpret_cast<const float4*>(x1 + (size_t)(h0 + 1) * Wn) + q;
    #pragma unroll 8
    for (int r = p; r < WHn; r += 4) {
      float4 a = r0[(size_t)r * (Wn / 4)];
      float4 b = r1[(size_t)r * (Wn / 4)];
      sS.x += a.x + b.x; sQ.x += a.x * a.x + b.x * b.x;
      sS.y += a.y + b.y; sQ.y += a.y * a.y + b.y * b.y;
      sS.z += a.z + b.z; sQ.z += a.z * a.z + b.z * b.z;
      sS.w += a.w + b.w; sQ.w += a.w * a.w + b.w * b.w;
    }
  }
  float accS, accQ;
  {
    float4* cc = reinterpret_cast<float4*>(&Ps[0][0][0]);   // [4][256] float4
    cc[p * 256 + 2 * q]     = make_float4(sS.x, sQ.x, sS.y, sQ.y);
    cc[p * 256 + 2 * q + 1] = make_float4(sS.z, sQ.z, sS.w, sQ.w);
    __syncthreads();
    const float2* cf = reinterpret_cast<const float2*>(&Ps[0][0][0]); // [4][512]
    float2 t0 = cf[0 * Wn + w], t1 = cf[1 * Wn + w];
    float2 t2 = cf[2 * Wn + w], t3 = cf[3 * Wn + w];
    accS = (t0.x + t1.x) + (t2.x + t3.x);
    accQ = (t0.y + t1.y) + (t2.y + t3.y);
    __syncthreads();   // Ps free for scan reuse
  }

  const float inv_n = 1.0f / (float)(WHn * WWn * 2);
  const int wp = min(max(w - PLn, 0), OWn - 1);   // out-col -> stat-col

  // slide prefetch: add rows h+228+j, sub rows h+1+j (j=0..7), 2 channels
  float pa0[8], pa1[8], ps0[8], ps1[8];
  auto prefetch = [&](int hb) {
    #pragma unroll
    for (int j = 0; j < 8; ++j) {
      int ra = min(hb + WHn + 1 + j, Hn - 1);   // clamp: guarded rows unused
      int rs = hb + 1 + j;                      // max 281+7=288 < 512
      pa0[j] = x0[(size_t)ra * Wn + w];
      pa1[j] = x1[(size_t)ra * Wn + w];
      ps0[j] = x0[(size_t)rs * Wn + w];
      ps1[j] = x1[(size_t)rs * Wn + w];
    }
  };
  prefetch(h0);

  // ---- Phase B: slide + scan + fused normalize, 8 rows/iter ----
  int buf = 0;
  for (int h = h0; h < h1; h += 8) {
    float2 v[8];
    v[0] = make_float2(accS, accQ);
    float s2 = accS, q2 = accQ;
    #pragma unroll
    for (int j = 0; j < 7; ++j) {
      s2 += (pa0[j] + pa1[j]) - (ps0[j] + ps1[j]);
      q2 += (pa0[j] * pa0[j] + pa1[j] * pa1[j])
          - (ps0[j] * ps0[j] + ps1[j] * ps1[j]);
      v[j + 1] = make_float2(s2, q2);
    }
    s2 += (pa0[7] + pa1[7]) - (ps0[7] + ps1[7]);
    q2 += (pa0[7] * pa0[7] + pa1[7] * pa1[7])
        - (ps0[7] * ps0[7] + ps1[7] * ps1[7]);
    accS = s2; accQ = q2;

    // issue next slide loads + this iteration's norm-x loads under the scan
    if (h + 8 < h1) prefetch(h + 8);
    float xa[8], xb[8];
    #pragma unroll
    for (int rr = 0; rr < 8; ++rr) {
      const size_t hh = (size_t)(h + PTn + rr) * Wn + w;  // max row 400 < 512
      xa[rr] = x0[hh];
      xb[rr] = x1[hh];
    }

    // 8 independent 512-wide inclusive scans (shared barriers)
    #pragma unroll
    for (int d = 1; d < 64; d <<= 1) {
      #pragma unroll
      for (int rr = 0; rr < 8; ++rr) {
        float sx = __shfl_up(v[rr].x, d, 64);
        float sy = __shfl_up(v[rr].y, d, 64);
        if (lane >= d) { v[rr].x += sx; v[rr].y += sy; }
      }
    }
    if (lane == 63) {
      #pragma unroll
      for (int rr = 0; rr < 8; ++rr) wsum[wid][rr] = v[rr];
    }
    __syncthreads();
    float2 off[8] = {{0.f,0.f},{0.f,0.f},{0.f,0.f},{0.f,0.f},
                     {0.f,0.f},{0.f,0.f},{0.f,0.f},{0.f,0.f}};
    #pragma unroll
    for (int i = 0; i < 7; ++i) {
      if (i < wid) {
        #pragma unroll
        for (int rr = 0; rr < 8; ++rr) {
          off[rr].x += wsum[i][rr].x; off[rr].y += wsum[i][rr].y;
        }
      }
    }
    #pragma unroll
    for (int rr = 0; rr < 8; ++rr)
      Ps[buf][rr][w + 1] = make_float2(v[rr].x + off[rr].x, v[rr].y + off[rr].y);
    __syncthreads();

    // fused normalize: out row hh = (h+rr)+113 from stat row h+rr.
    // No trailing barrier: next iter writes Ps[buf^1]; wsum rewrites only
    // happen after this barrier (safe, reads were before it).
    #pragma unroll
    for (int rr = 0; rr < 8; ++rr) {
      if (h + rr < h1) {
        float2 hi = Ps[buf][rr][wp + WWn + 1];
        float2 lo = Ps[buf][rr][wp + 1];
        float S = hi.x - lo.x;
        float Q = hi.y - lo.y;
        float mean = S * inv_n;
        float var = (Q - S * S * inv_n) * inv_n;
        float istd = rsqrtf(var + EPSn);
        if ((chunk == 0 && h + rr == 0) || (chunk == 3 && h + rr == 284))
          bstat[w & 3][w >> 2] = make_float2(mean, istd);
        const size_t oo = (size_t)(h + PTn + rr) * Wn + w;
        o0[oo] = (xa[rr] - mean) * istd * wt0 + bs0;
        o1[oo] = (xb[rr] - mean) * istd * wt1 + bs1;
      }
    }
    buf ^= 1;
  }

  // ---- Phase C: replicate-pad border rows (chunk 0: 0..112, chunk 3: 398..511)
  if (chunk == 0 || chunk == 3) {
    __syncthreads();   // bstat visibility across threads
    const int row0 = (chunk == 0) ? 0 : 398;
    const int nrows = (chunk == 0) ? PTn : Hn - 398;   // 113 / 114
    const int total = nrows * 256;                     // 2 ch x 128 quads
    const float4* __restrict__ xf0 = reinterpret_cast<const float4*>(x0);
    const float4* __restrict__ xf1 = reinterpret_cast<const float4*>(x1);
    float4* __restrict__ of0 = reinterpret_cast<float4*>(o0);
    float4* __restrict__ of1 = reinterpret_cast<float4*>(o1);
    for (int i = w; i < total; i += 512) {
      const int qq = i & 127;
      const int ch = (i >> 7) & 1;
      const int row = row0 + (i >> 8);
      const size_t idx = (size_t)row * (Wn / 4) + qq;
      const float4 xv = ch ? xf1[idx] : xf0[idx];
      const float wt = ch ? wt1 : wt0;
      const float bsv = ch ? bs1 : bs0;
      const float2 m0 = bstat[0][qq];
      const float2 m1 = bstat[1][qq];
      const float2 m2 = bstat[2][qq];
      const float2 m3 = bstat[3][qq];
      float4 ov;
      ov.x = (xv.x - m0.x) * m0.y * wt + bsv;
      ov.y = (xv.y - m1.x) * m1.y * wt + bsv;
      ov.z = (xv.z - m2.x) * m2.y * wt + bsv;
      ov.w = (xv.w - m3.x) * m3.y * wt + bsv;
      if (ch) of1[idx] = ov; else of0[idx] = ov;
    }
  }
}

extern "C" void kernel_launch(void* const* d_in, const int* in_sizes, int n_in,
                              void* d_out, int out_size, void* d_ws, size_t ws_size,
                              hipStream_t stream) {
  const float* x = (const float*)d_in[0];
  const float* weight = (const float*)d_in[1];
  const float* bias = (const float*)d_in[2];
  float* out = (float*)d_out;

  hipLaunchKernelGGL(lcn_fused, dim3(128 * 4), dim3(512), 0, stream,
                     x, weight, bias, out);
}